// Round 1
// baseline (814.302 us; speedup 1.0000x reference)
//
#include <hip/hip_runtime.h>

#define N_NODES 100000
#define N_EDGES 1280000
#define N_GRAPHS 512
#define SCAN_BLOCKS 391   // ceil(100000/256)

// ---------------- degree / norm ----------------

__global__ void count_deg(const int* __restrict__ dst, int* __restrict__ cnt) {
    int e = blockIdx.x * blockDim.x + threadIdx.x;
    if (e < N_EDGES) atomicAdd(&cnt[dst[e]], 1);
}

__global__ void compute_dinv(const int* __restrict__ cnt, float* __restrict__ dinv) {
    int i = blockIdx.x * blockDim.x + threadIdx.x;
    if (i < N_NODES) dinv[i] = 1.0f / sqrtf((float)cnt[i] + 1.0f);
}

// ---------------- exclusive prefix scan (3-kernel) ----------------

__global__ void scan1(const int* __restrict__ cnt, int* __restrict__ offs, int* __restrict__ bsum) {
    __shared__ int s[256];
    int t = threadIdx.x;
    int i = blockIdx.x * 256 + t;
    int v = (i < N_NODES) ? cnt[i] : 0;
    s[t] = v; __syncthreads();
    for (int d = 1; d < 256; d <<= 1) {
        int x = (t >= d) ? s[t - d] : 0;
        __syncthreads();
        s[t] += x;
        __syncthreads();
    }
    if (i < N_NODES) offs[i] = s[t] - v;
    if (t == 255) bsum[blockIdx.x] = s[t];
}

__global__ void scan2(int* __restrict__ bsum, int nb) {
    __shared__ int s[512];
    int t = threadIdx.x;
    int v = (t < nb) ? bsum[t] : 0;
    s[t] = v; __syncthreads();
    for (int d = 1; d < 512; d <<= 1) {
        int x = (t >= d) ? s[t - d] : 0;
        __syncthreads();
        s[t] += x;
        __syncthreads();
    }
    if (t < nb) bsum[t] = s[t] - v;
}

__global__ void scan3(int* __restrict__ offs, const int* __restrict__ bsum) {
    int i = blockIdx.x * 256 + threadIdx.x;
    if (i < N_NODES) offs[i] += bsum[blockIdx.x];
    if (i == 0) offs[N_NODES] = N_EDGES;
}

// ---------------- CSR fill ----------------

__global__ void fill_csr(const int* __restrict__ src, const int* __restrict__ dst,
                         const int* __restrict__ offs, int* __restrict__ cursor,
                         const float* __restrict__ dinv,
                         int* __restrict__ csr_src, float* __restrict__ csr_norm) {
    int e = blockIdx.x * blockDim.x + threadIdx.x;
    if (e < N_EDGES) {
        int d = dst[e], s = src[e];
        int p = offs[d] + atomicAdd(&cursor[d], 1);
        csr_src[p] = s;
        csr_norm[p] = dinv[s] * dinv[d];
    }
}

// ---------------- fp32 GEMM [N x 64] @ [64 x 64] ----------------

__global__ __launch_bounds__(256) void gemm64(const float* __restrict__ X,
                                              const float* __restrict__ W,
                                              float* __restrict__ H) {
    __shared__ float Xt[64][68];   // transposed tile: Xt[k][node], pad to 68 for bank spread
    __shared__ float Ws[64][64];   // Ws[k][j]
    int t = threadIdx.x;
    int base = blockIdx.x * 64;

    // load W (4096 floats) with float4
    {
        const float4* Wv = (const float4*)W;
        float4* Wsv = (float4*)Ws;
        Wsv[t]        = Wv[t];
        Wsv[t + 256]  = Wv[t + 256];
        Wsv[t + 512]  = Wv[t + 512];
        Wsv[t + 768]  = Wv[t + 768];
    }
    // load X tile, transpose into LDS
    {
        int r = t >> 2;
        int k0 = (t & 3) * 16;
        int row = base + r;
        if (row < N_NODES) {
            const float4* xr = (const float4*)(X + row * 64 + k0);
            #pragma unroll
            for (int q = 0; q < 4; q++) {
                float4 v = xr[q];
                int k = k0 + q * 4;
                Xt[k + 0][r] = v.x; Xt[k + 1][r] = v.y;
                Xt[k + 2][r] = v.z; Xt[k + 3][r] = v.w;
            }
        } else {
            #pragma unroll
            for (int q = 0; q < 4; q++) {
                int k = k0 + q * 4;
                Xt[k][r] = 0.f; Xt[k + 1][r] = 0.f; Xt[k + 2][r] = 0.f; Xt[k + 3][r] = 0.f;
            }
        }
    }
    __syncthreads();

    int tx = t & 15, ty = t >> 4;
    int j0 = tx * 4, n0 = ty * 4;
    float acc[4][4] = {};
    #pragma unroll
    for (int k = 0; k < 64; k++) {
        float4 a = *(const float4*)&Xt[k][n0];
        float4 w = *(const float4*)&Ws[k][j0];
        acc[0][0] += a.x * w.x; acc[0][1] += a.x * w.y; acc[0][2] += a.x * w.z; acc[0][3] += a.x * w.w;
        acc[1][0] += a.y * w.x; acc[1][1] += a.y * w.y; acc[1][2] += a.y * w.z; acc[1][3] += a.y * w.w;
        acc[2][0] += a.z * w.x; acc[2][1] += a.z * w.y; acc[2][2] += a.z * w.z; acc[2][3] += a.z * w.w;
        acc[3][0] += a.w * w.x; acc[3][1] += a.w * w.y; acc[3][2] += a.w * w.z; acc[3][3] += a.w * w.w;
    }
    #pragma unroll
    for (int i = 0; i < 4; i++) {
        int row = base + n0 + i;
        if (row < N_NODES) {
            float4 o; o.x = acc[i][0]; o.y = acc[i][1]; o.z = acc[i][2]; o.w = acc[i][3];
            *(float4*)(H + row * 64 + j0) = o;
        }
    }
}

// ---------------- aggregation: wave per node, lane = feature ----------------

__global__ __launch_bounds__(256) void agg_gcn(const float* __restrict__ H,
                                               const int* __restrict__ offs,
                                               const int* __restrict__ csr_src,
                                               const float* __restrict__ csr_norm,
                                               const float* __restrict__ dinv,
                                               const float* __restrict__ bias,
                                               float* __restrict__ Out) {
    int wid = (blockIdx.x * 256 + threadIdx.x) >> 6;
    int lane = threadIdx.x & 63;
    if (wid >= N_NODES) return;
    int beg = offs[wid], end = offs[wid + 1];
    float di = dinv[wid];
    float acc = H[wid * 64 + lane] * (di * di);   // self-loop term
    for (int e0 = beg; e0 < end; e0 += 64) {
        int sv = 0; float nv = 0.f;
        if (e0 + lane < end) { sv = csr_src[e0 + lane]; nv = csr_norm[e0 + lane]; }
        int m = min(64, end - e0);
        for (int j = 0; j < m; j++) {
            int   s  = __shfl(sv, j);
            float nm = __shfl(nv, j);
            acc += H[s * 64 + lane] * nm;
        }
    }
    Out[wid * 64 + lane] = fmaxf(acc + bias[lane], 0.f);
}

// ---------------- pool + head ----------------

__global__ __launch_bounds__(256) void pool_dot(const float* __restrict__ H,
                                                const int* __restrict__ batch,
                                                const float* __restrict__ fcw,
                                                float* __restrict__ gsum,
                                                int* __restrict__ gcnt) {
    int wid = (blockIdx.x * 256 + threadIdx.x) >> 6;
    int lane = threadIdx.x & 63;
    if (wid >= N_NODES) return;
    float p = H[wid * 64 + lane] * fcw[lane];
    #pragma unroll
    for (int o = 32; o > 0; o >>= 1) p += __shfl_xor(p, o);
    if (lane == 0) {
        int g = batch[wid];
        atomicAdd(&gsum[g], p);
        atomicAdd(&gcnt[g], 1);
    }
}

__global__ void finalize(const float* __restrict__ gsum, const int* __restrict__ gcnt,
                         const float* __restrict__ fcb, float* __restrict__ out) {
    int g = blockIdx.x * blockDim.x + threadIdx.x;
    if (g < N_GRAPHS) out[g] = gsum[g] / fmaxf((float)gcnt[g], 1.f) + fcb[0];
}

// ---------------- launch ----------------

extern "C" void kernel_launch(void* const* d_in, const int* in_sizes, int n_in,
                              void* d_out, int out_size, void* d_ws, size_t ws_size,
                              hipStream_t stream) {
    const float* x    = (const float*)d_in[0];
    const int*   ei   = (const int*)d_in[1];
    const int*   batch= (const int*)d_in[2];
    const float* w0   = (const float*)d_in[3];
    const float* b0   = (const float*)d_in[4];
    const float* w1   = (const float*)d_in[5];
    const float* b1   = (const float*)d_in[6];
    const float* w2   = (const float*)d_in[7];
    const float* b2   = (const float*)d_in[8];
    const float* fcw  = (const float*)d_in[9];
    const float* fcb  = (const float*)d_in[10];
    float* out = (float*)d_out;

    const int* src_e = ei;              // edge_index[0]
    const int* dst_e = ei + N_EDGES;    // edge_index[1]

    // workspace layout (all 16B-aligned)
    char* w = (char*)d_ws;
    size_t o = 0;
    int*   deg_cnt  = (int*)(w + o);   o += (size_t)N_NODES * 4;          // 400000
    float* dinv     = (float*)(w + o); o += (size_t)N_NODES * 4;          // 400000
    int*   offs     = (int*)(w + o);   o += (size_t)(N_NODES + 8) * 4;    // 400032
    int*   cursor   = (int*)(w + o);   o += (size_t)N_NODES * 4;          // 400000
    int*   bsum     = (int*)(w + o);   o += 512 * 4;                      // 2048
    int*   csr_src  = (int*)(w + o);   o += (size_t)N_EDGES * 4;          // 5.12MB
    float* csr_norm = (float*)(w + o); o += (size_t)N_EDGES * 4;          // 5.12MB
    float* bufA     = (float*)(w + o); o += (size_t)N_NODES * 64 * 4;     // 25.6MB
    float* bufB     = (float*)(w + o); o += (size_t)N_NODES * 64 * 4;     // 25.6MB
    float* gsum     = (float*)(w + o); o += N_GRAPHS * 4;
    int*   gcnt     = (int*)(w + o);   o += N_GRAPHS * 4;

    hipMemsetAsync(deg_cnt, 0, (size_t)N_NODES * 4, stream);
    hipMemsetAsync(cursor,  0, (size_t)N_NODES * 4, stream);
    hipMemsetAsync(gsum,    0, N_GRAPHS * 4, stream);
    hipMemsetAsync(gcnt,    0, N_GRAPHS * 4, stream);

    count_deg<<<(N_EDGES + 255) / 256, 256, 0, stream>>>(dst_e, deg_cnt);
    compute_dinv<<<(N_NODES + 255) / 256, 256, 0, stream>>>(deg_cnt, dinv);
    scan1<<<SCAN_BLOCKS, 256, 0, stream>>>(deg_cnt, offs, bsum);
    scan2<<<1, 512, 0, stream>>>(bsum, SCAN_BLOCKS);
    scan3<<<SCAN_BLOCKS, 256, 0, stream>>>(offs, bsum);
    fill_csr<<<(N_EDGES + 255) / 256, 256, 0, stream>>>(src_e, dst_e, offs, cursor, dinv,
                                                        csr_src, csr_norm);

    const int GEMM_BLOCKS = (N_NODES + 63) / 64;   // 1563
    const int AGG_BLOCKS  = (N_NODES + 3) / 4;     // 25000 (4 waves/block, wave per node)

    gemm64<<<GEMM_BLOCKS, 256, 0, stream>>>(x, w0, bufA);
    agg_gcn<<<AGG_BLOCKS, 256, 0, stream>>>(bufA, offs, csr_src, csr_norm, dinv, b0, bufB);

    gemm64<<<GEMM_BLOCKS, 256, 0, stream>>>(bufB, w1, bufA);
    agg_gcn<<<AGG_BLOCKS, 256, 0, stream>>>(bufA, offs, csr_src, csr_norm, dinv, b1, bufB);

    gemm64<<<GEMM_BLOCKS, 256, 0, stream>>>(bufB, w2, bufA);
    agg_gcn<<<AGG_BLOCKS, 256, 0, stream>>>(bufA, offs, csr_src, csr_norm, dinv, b2, bufB);

    pool_dot<<<AGG_BLOCKS, 256, 0, stream>>>(bufB, batch, fcw, gsum, gcnt);
    finalize<<<2, 256, 0, stream>>>(gsum, gcnt, fcb, out);
}

// Round 2
// 610.056 us; speedup vs baseline: 1.3348x; 1.3348x over previous
//
#include <hip/hip_runtime.h>

#define N_NODES 100000
#define N_EDGES 1280000
#define N_GRAPHS 512
#define SCAN_BLOCKS 391   // ceil(100000/256)

// ---------------- degree / norm ----------------

__global__ void count_deg(const int* __restrict__ dst, int* __restrict__ cnt) {
    int e = blockIdx.x * blockDim.x + threadIdx.x;
    if (e < N_EDGES) atomicAdd(&cnt[dst[e]], 1);
}

__global__ void compute_dinv(const int* __restrict__ cnt, float* __restrict__ dinv) {
    int i = blockIdx.x * blockDim.x + threadIdx.x;
    if (i < N_NODES) dinv[i] = 1.0f / sqrtf((float)cnt[i] + 1.0f);
}

// ---------------- exclusive prefix scan (3-kernel) ----------------

__global__ void scan1(const int* __restrict__ cnt, int* __restrict__ offs, int* __restrict__ bsum) {
    __shared__ int s[256];
    int t = threadIdx.x;
    int i = blockIdx.x * 256 + t;
    int v = (i < N_NODES) ? cnt[i] : 0;
    s[t] = v; __syncthreads();
    for (int d = 1; d < 256; d <<= 1) {
        int x = (t >= d) ? s[t - d] : 0;
        __syncthreads();
        s[t] += x;
        __syncthreads();
    }
    if (i < N_NODES) offs[i] = s[t] - v;
    if (t == 255) bsum[blockIdx.x] = s[t];
}

__global__ void scan2(int* __restrict__ bsum, int nb) {
    __shared__ int s[512];
    int t = threadIdx.x;
    int v = (t < nb) ? bsum[t] : 0;
    s[t] = v; __syncthreads();
    for (int d = 1; d < 512; d <<= 1) {
        int x = (t >= d) ? s[t - d] : 0;
        __syncthreads();
        s[t] += x;
        __syncthreads();
    }
    if (t < nb) bsum[t] = s[t] - v;
}

__global__ void scan3(int* __restrict__ offs, const int* __restrict__ bsum) {
    int i = blockIdx.x * 256 + threadIdx.x;
    if (i < N_NODES) offs[i] += bsum[blockIdx.x];
    if (i == 0) offs[N_NODES] = N_EDGES;
}

// ---------------- CSR fill ----------------

__global__ void fill_csr(const int* __restrict__ src, const int* __restrict__ dst,
                         const int* __restrict__ offs, int* __restrict__ cursor,
                         const float* __restrict__ dinv,
                         int* __restrict__ csr_src, float* __restrict__ csr_norm) {
    int e = blockIdx.x * blockDim.x + threadIdx.x;
    if (e < N_EDGES) {
        int d = dst[e], s = src[e];
        int p = offs[d] + atomicAdd(&cursor[d], 1);
        csr_src[p] = s;
        csr_norm[p] = dinv[s] * dinv[d];
    }
}

// ---------------- fp32 GEMM [N x 64] @ [64 x 64] ----------------

__global__ __launch_bounds__(256) void gemm64(const float* __restrict__ X,
                                              const float* __restrict__ W,
                                              float* __restrict__ H) {
    __shared__ float Xt[64][68];   // transposed tile: Xt[k][node]
    __shared__ float Ws[64][64];   // Ws[k][j]
    int t = threadIdx.x;
    int base = blockIdx.x * 64;

    {
        const float4* Wv = (const float4*)W;
        float4* Wsv = (float4*)Ws;
        Wsv[t]        = Wv[t];
        Wsv[t + 256]  = Wv[t + 256];
        Wsv[t + 512]  = Wv[t + 512];
        Wsv[t + 768]  = Wv[t + 768];
    }
    {
        int r = t >> 2;
        int k0 = (t & 3) * 16;
        int row = base + r;
        if (row < N_NODES) {
            const float4* xr = (const float4*)(X + row * 64 + k0);
            #pragma unroll
            for (int q = 0; q < 4; q++) {
                float4 v = xr[q];
                int k = k0 + q * 4;
                Xt[k + 0][r] = v.x; Xt[k + 1][r] = v.y;
                Xt[k + 2][r] = v.z; Xt[k + 3][r] = v.w;
            }
        } else {
            #pragma unroll
            for (int q = 0; q < 4; q++) {
                int k = k0 + q * 4;
                Xt[k][r] = 0.f; Xt[k + 1][r] = 0.f; Xt[k + 2][r] = 0.f; Xt[k + 3][r] = 0.f;
            }
        }
    }
    __syncthreads();

    int tx = t & 15, ty = t >> 4;
    int j0 = tx * 4, n0 = ty * 4;
    float acc[4][4] = {};
    #pragma unroll
    for (int k = 0; k < 64; k++) {
        float4 a = *(const float4*)&Xt[k][n0];
        float4 w = *(const float4*)&Ws[k][j0];
        acc[0][0] += a.x * w.x; acc[0][1] += a.x * w.y; acc[0][2] += a.x * w.z; acc[0][3] += a.x * w.w;
        acc[1][0] += a.y * w.x; acc[1][1] += a.y * w.y; acc[1][2] += a.y * w.z; acc[1][3] += a.y * w.w;
        acc[2][0] += a.z * w.x; acc[2][1] += a.z * w.y; acc[2][2] += a.z * w.z; acc[2][3] += a.z * w.w;
        acc[3][0] += a.w * w.x; acc[3][1] += a.w * w.y; acc[3][2] += a.w * w.z; acc[3][3] += a.w * w.w;
    }
    #pragma unroll
    for (int i = 0; i < 4; i++) {
        int row = base + n0 + i;
        if (row < N_NODES) {
            float4 o; o.x = acc[i][0]; o.y = acc[i][1]; o.z = acc[i][2]; o.w = acc[i][3];
            *(float4*)(H + row * 64 + j0) = o;
        }
    }
}

// ---------------- aggregation: wave per node, lane = feature ----------------

__global__ __launch_bounds__(256) void agg_gcn(const float* __restrict__ H,
                                               const int* __restrict__ offs,
                                               const int* __restrict__ csr_src,
                                               const float* __restrict__ csr_norm,
                                               const float* __restrict__ dinv,
                                               const float* __restrict__ bias,
                                               float* __restrict__ Out) {
    int wid = (blockIdx.x * 256 + threadIdx.x) >> 6;
    int lane = threadIdx.x & 63;
    if (wid >= N_NODES) return;
    int beg = offs[wid], end = offs[wid + 1];
    float di = dinv[wid];
    float acc = H[wid * 64 + lane] * (di * di);   // self-loop term
    for (int e0 = beg; e0 < end; e0 += 64) {
        int sv = 0; float nv = 0.f;
        if (e0 + lane < end) { sv = csr_src[e0 + lane]; nv = csr_norm[e0 + lane]; }
        int m = min(64, end - e0);
        for (int j = 0; j < m; j++) {
            int   s  = __shfl(sv, j);
            float nm = __shfl(nv, j);
            acc += H[s * 64 + lane] * nm;
        }
    }
    Out[wid * 64 + lane] = fmaxf(acc + bias[lane], 0.f);
}

// ---- layer-3 variant: fuse bias+relu+head-dot, write p[node] only ----

__global__ __launch_bounds__(256) void agg_gcn_pool(const float* __restrict__ H,
                                                    const int* __restrict__ offs,
                                                    const int* __restrict__ csr_src,
                                                    const float* __restrict__ csr_norm,
                                                    const float* __restrict__ dinv,
                                                    const float* __restrict__ bias,
                                                    const float* __restrict__ fcw,
                                                    float* __restrict__ p) {
    int wid = (blockIdx.x * 256 + threadIdx.x) >> 6;
    int lane = threadIdx.x & 63;
    if (wid >= N_NODES) return;
    int beg = offs[wid], end = offs[wid + 1];
    float di = dinv[wid];
    float acc = H[wid * 64 + lane] * (di * di);
    for (int e0 = beg; e0 < end; e0 += 64) {
        int sv = 0; float nv = 0.f;
        if (e0 + lane < end) { sv = csr_src[e0 + lane]; nv = csr_norm[e0 + lane]; }
        int m = min(64, end - e0);
        for (int j = 0; j < m; j++) {
            int   s  = __shfl(sv, j);
            float nm = __shfl(nv, j);
            acc += H[s * 64 + lane] * nm;
        }
    }
    float v = fmaxf(acc + bias[lane], 0.f) * fcw[lane];
    #pragma unroll
    for (int o = 32; o > 0; o >>= 1) v += __shfl_xor(v, o);
    if (lane == 0) p[wid] = v;
}

// ---------------- per-graph segmented mean via binary search (no atomics) ----

__device__ inline int lower_bound_batch(const int* __restrict__ batch, int key) {
    int lo = 0, hi = N_NODES;
    while (lo < hi) {
        int mid = (lo + hi) >> 1;
        if (batch[mid] < key) lo = mid + 1; else hi = mid;
    }
    return lo;
}

__global__ __launch_bounds__(256) void graph_reduce(const float* __restrict__ p,
                                                    const int* __restrict__ batch,
                                                    const float* __restrict__ fcb,
                                                    float* __restrict__ out) {
    __shared__ float red[4];
    int g = blockIdx.x;
    int s0 = lower_bound_batch(batch, g);
    int s1 = lower_bound_batch(batch, g + 1);
    float acc = 0.f;
    for (int i = s0 + threadIdx.x; i < s1; i += 256) acc += p[i];
    #pragma unroll
    for (int o = 32; o > 0; o >>= 1) acc += __shfl_xor(acc, o);
    int lane = threadIdx.x & 63, wv = threadIdx.x >> 6;
    if (lane == 0) red[wv] = acc;
    __syncthreads();
    if (threadIdx.x == 0) {
        float sum = red[0] + red[1] + red[2] + red[3];
        out[g] = sum / fmaxf((float)(s1 - s0), 1.f) + fcb[0];
    }
}

// ---------------- launch ----------------

extern "C" void kernel_launch(void* const* d_in, const int* in_sizes, int n_in,
                              void* d_out, int out_size, void* d_ws, size_t ws_size,
                              hipStream_t stream) {
    const float* x    = (const float*)d_in[0];
    const int*   ei   = (const int*)d_in[1];
    const int*   batch= (const int*)d_in[2];
    const float* w0   = (const float*)d_in[3];
    const float* b0   = (const float*)d_in[4];
    const float* w1   = (const float*)d_in[5];
    const float* b1   = (const float*)d_in[6];
    const float* w2   = (const float*)d_in[7];
    const float* b2   = (const float*)d_in[8];
    const float* fcw  = (const float*)d_in[9];
    const float* fcb  = (const float*)d_in[10];
    float* out = (float*)d_out;

    const int* src_e = ei;              // edge_index[0]
    const int* dst_e = ei + N_EDGES;    // edge_index[1]

    char* w = (char*)d_ws;
    size_t o = 0;
    int*   deg_cnt  = (int*)(w + o);   o += (size_t)N_NODES * 4;
    float* dinv     = (float*)(w + o); o += (size_t)N_NODES * 4;
    int*   offs     = (int*)(w + o);   o += (size_t)(N_NODES + 8) * 4;
    int*   cursor   = (int*)(w + o);   o += (size_t)N_NODES * 4;
    int*   bsum     = (int*)(w + o);   o += 512 * 4;
    int*   csr_src  = (int*)(w + o);   o += (size_t)N_EDGES * 4;
    float* csr_norm = (float*)(w + o); o += (size_t)N_EDGES * 4;
    float* bufA     = (float*)(w + o); o += (size_t)N_NODES * 64 * 4;
    float* bufB     = (float*)(w + o); o += (size_t)N_NODES * 64 * 4;
    float* pvec     = (float*)(w + o); o += (size_t)N_NODES * 4;

    hipMemsetAsync(deg_cnt, 0, (size_t)N_NODES * 4, stream);
    hipMemsetAsync(cursor,  0, (size_t)N_NODES * 4, stream);

    count_deg<<<(N_EDGES + 255) / 256, 256, 0, stream>>>(dst_e, deg_cnt);
    compute_dinv<<<(N_NODES + 255) / 256, 256, 0, stream>>>(deg_cnt, dinv);
    scan1<<<SCAN_BLOCKS, 256, 0, stream>>>(deg_cnt, offs, bsum);
    scan2<<<1, 512, 0, stream>>>(bsum, SCAN_BLOCKS);
    scan3<<<SCAN_BLOCKS, 256, 0, stream>>>(offs, bsum);
    fill_csr<<<(N_EDGES + 255) / 256, 256, 0, stream>>>(src_e, dst_e, offs, cursor, dinv,
                                                        csr_src, csr_norm);

    const int GEMM_BLOCKS = (N_NODES + 63) / 64;   // 1563
    const int AGG_BLOCKS  = (N_NODES + 3) / 4;     // 25000

    gemm64<<<GEMM_BLOCKS, 256, 0, stream>>>(x, w0, bufA);
    agg_gcn<<<AGG_BLOCKS, 256, 0, stream>>>(bufA, offs, csr_src, csr_norm, dinv, b0, bufB);

    gemm64<<<GEMM_BLOCKS, 256, 0, stream>>>(bufB, w1, bufA);
    agg_gcn<<<AGG_BLOCKS, 256, 0, stream>>>(bufA, offs, csr_src, csr_norm, dinv, b1, bufB);

    gemm64<<<GEMM_BLOCKS, 256, 0, stream>>>(bufB, w2, bufA);
    agg_gcn_pool<<<AGG_BLOCKS, 256, 0, stream>>>(bufA, offs, csr_src, csr_norm, dinv, b2,
                                                 fcw, pvec);

    graph_reduce<<<N_GRAPHS, 256, 0, stream>>>(pvec, batch, fcb, out);
}